// Round 6
// baseline (548.997 us; speedup 1.0000x reference)
//
#include <hip/hip_runtime.h>
#include <math.h>

#define DIM 128

typedef __attribute__((ext_vector_type(8))) short bf16x8;
typedef __attribute__((ext_vector_type(4))) float f32x4;

__device__ __forceinline__ ushort f2bf(float f) {  // RTNE
  unsigned u = __float_as_uint(f);
  return (ushort)((u + 0x7FFFu + ((u >> 16) & 1u)) >> 16);
}
__device__ __forceinline__ float bf2f(ushort h) {
  return __uint_as_float(((unsigned)h) << 16);
}

// ---------------- K1: hist (atomic floor) || byte-minimal gemm1 || wsplit(W2) ----------------
// Model (R0-R5): T = T_atomic(~55us) + co_bytes/6TB/s, valid at occupancy >=~45%.
// gemm1 bytes must be paid somewhere -> ride them on the atomic floor for free-ish.
// gemm1 fixes vs R5: (1) one block computes BOTH x@W1l and x@W1r -> x read ONCE
// (R5 FETCH was 2x: 96 MB); (2) epilogue staged through LDS -> coalesced int4 row
// writes (R5's scalar ushort stores caused 3x write-allocate: 152 MB).
__global__ __launch_bounds__(256, 4) void prep6_kernel(
    const int* __restrict__ dst, unsigned* __restrict__ deg, unsigned* __restrict__ rank, int E,
    const float* __restrict__ x,
    const float* __restrict__ W1l, const float* __restrict__ W1r,
    ushort* __restrict__ xl, ushort* __restrict__ xr,
    const float* __restrict__ W2l, const float* __restrict__ W2r,
    ushort* __restrict__ tabs, int H, int G64, int N) {
  __shared__ ushort As[64 * 32];       // 4 KB: x tile (64 rows x 32 k), bf16 swizzled
  __shared__ ushort Bs[2 * 128 * 32];  // 16 KB: both W tiles; epilogue reuses as 64x128 stage
  const int tid = threadIdx.x;
  const int bid = blockIdx.x;
  const int r5 = bid % 5;
  const int q5 = bid / 5;

  if (r5 != 4) {  // histogram role: 4/5 of blocks
    int hid = q5 * 4 + r5;
    if (hid < H) {
      int gid = hid * 256 + tid;
      if (gid < E) rank[gid] = atomicAdd(&deg[dst[gid]], 1u);
    }
    return;
  }
  int aid = q5;
  if (aid >= G64) {  // wsplit role: transpose+cast W2l/W2r to bf16 tabs
    int aid2 = aid - G64;
    if (aid2 < 128) {
      int m = aid2 >> 6;
      const float* W = m ? W2r : W2l;
      ushort* Ht = tabs + (size_t)m * 16384;
      int idx = (aid2 & 63) * 256 + tid;
      int k = idx >> 7, n = idx & 127;
      Ht[n * DIM + k] = f2bf(W[idx]);
    }
    return;
  }

  // ---- GEMM role: rows [bm, bm+64) of BOTH xl = x@W1l and xr = x@W1r ----
  const int bm = aid * 64;
  const int wave = tid >> 6;
  const int lane = tid & 63;
  const int l15 = lane & 15;
  const int quad = lane >> 4;

  f32x4 acc[2][8];  // [mat][col-block of 16]
#pragma unroll
  for (int m = 0; m < 2; ++m)
#pragma unroll
    for (int j = 0; j < 8; ++j) acc[m][j] = (f32x4){0.f, 0.f, 0.f, 0.f};

  for (int g = 0; g < 4; ++g) {
    const int kt = g << 5;
    __syncthreads();
    // stage A: x[bm..bm+63][kt..kt+31] fp32 -> bf16 swizzled (512 float4 loads)
#pragma unroll
    for (int c = 0; c < 2; ++c) {
      int flat = c * 256 + tid;  // 0..511
      int row = flat >> 3;       // 0..63
      int q4 = flat & 7;         // k = q4*4
      int grow = bm + row;
      if (grow >= N) grow = N - 1;
      float4 v = *(const float4*)(x + (size_t)grow * DIM + kt + q4 * 4);
      int kb = q4 >> 1, ki = (q4 & 1) << 2;
      uint2 pk;
      pk.x = (unsigned)f2bf(v.x) | ((unsigned)f2bf(v.y) << 16);
      pk.y = (unsigned)f2bf(v.z) | ((unsigned)f2bf(v.w) << 16);
      *(uint2*)(&As[row * 32 + ((kb ^ (row & 3)) << 3) + ki]) = pk;
    }
    // stage B: BOTH W mats [kt..kt+31][0..127] -> Bs[m][n][k] bf16 (transpose in store)
#pragma unroll
    for (int c = 0; c < 32; ++c) {
      int idx = c * 256 + tid;  // 0..8191
      int m = idx >> 12;
      int rem = idx & 4095;
      int kk = rem >> 7;   // 0..31
      int n = rem & 127;   // 0..127
      const float* W = m ? W1r : W1l;
      Bs[m * 4096 + n * 32 + (((kk >> 3) ^ (n & 3)) << 3) + (kk & 7)] =
          f2bf(W[(size_t)(kt + kk) * DIM + n]);
    }
    __syncthreads();
    int ar = (wave << 4) + l15;  // this wave's 16 rows
    bf16x8 af = *(const bf16x8*)(&As[ar * 32 + ((quad ^ (ar & 3)) << 3)]);
#pragma unroll
    for (int m = 0; m < 2; ++m)
#pragma unroll
      for (int j = 0; j < 8; ++j) {
        int br = (j << 4) + l15;
        bf16x8 bfr = *(const bf16x8*)(&Bs[m * 4096 + br * 32 + ((quad ^ (br & 3)) << 3)]);
        acc[m][j] = __builtin_amdgcn_mfma_f32_16x16x32_bf16(af, bfr, acc[m][j], 0, 0, 0);
      }
  }

  // epilogue: per mat, stage 64x128 bf16 in Bs then coalesced int4 row writes
#pragma unroll
  for (int m = 0; m < 2; ++m) {
    __syncthreads();  // Bs free (or prev mat's reads done)
#pragma unroll
    for (int j = 0; j < 8; ++j)
#pragma unroll
      for (int r = 0; r < 4; ++r) {
        int rowl = (wave << 4) + (quad << 2) + r;  // 0..63
        Bs[rowl * 128 + (j << 4) + l15] = f2bf(acc[m][j][r]);
      }
    __syncthreads();
    ushort* out = m ? xr : xl;
#pragma unroll
    for (int c = 0; c < 4; ++c) {
      int flat = c * 256 + tid;  // int4 id 0..1023
      int row = flat >> 4;       // 0..63
      int grow = bm + row;
      if (grow < N)
        *(int4*)(out + (size_t)grow * DIM + (flat & 15) * 8) = *(const int4*)(&Bs[flat * 8]);
    }
  }
}

// ---------------- two-level exclusive scan over deg (+ fused dinv) ----------------
__global__ __launch_bounds__(256) void scan_block_kernel(const unsigned* __restrict__ deg,
                                                         unsigned* __restrict__ excl,
                                                         unsigned* __restrict__ partial,
                                                         float* __restrict__ dinv, int N) {
  __shared__ unsigned s[256];
  int i = blockIdx.x * 256 + threadIdx.x;
  unsigned v = (i < N) ? deg[i] : 0u;
  if (i < N) dinv[i] = 1.0f / fmaxf((float)v, 1.0f);
  s[threadIdx.x] = v;
  __syncthreads();
#pragma unroll
  for (int d = 1; d < 256; d <<= 1) {
    unsigned t = (threadIdx.x >= d) ? s[threadIdx.x - d] : 0u;
    __syncthreads();
    s[threadIdx.x] += t;
    __syncthreads();
  }
  if (i < N) excl[i] = s[threadIdx.x] - v;
  if (threadIdx.x == 255) partial[blockIdx.x] = s[255];
}

__global__ __launch_bounds__(256) void scan_partials_kernel(unsigned* __restrict__ partial, int B) {
  __shared__ unsigned s[256];
  __shared__ unsigned carry;
  if (threadIdx.x == 0) carry = 0u;
  __syncthreads();
  for (int base = 0; base < B; base += 256) {
    int i = base + threadIdx.x;
    unsigned v = (i < B) ? partial[i] : 0u;
    s[threadIdx.x] = v;
    __syncthreads();
#pragma unroll
    for (int d = 1; d < 256; d <<= 1) {
      unsigned t = (threadIdx.x >= d) ? s[threadIdx.x - d] : 0u;
      __syncthreads();
      s[threadIdx.x] += t;
      __syncthreads();
    }
    if (i < B) partial[i] = carry + s[threadIdx.x] - v;
    __syncthreads();
    if (threadIdx.x == 0) carry += s[255];
    __syncthreads();
  }
}

__global__ __launch_bounds__(256) void add_offsets_kernel(const unsigned* __restrict__ excl,
                                                          const unsigned* __restrict__ partial,
                                                          unsigned* __restrict__ off, int N, int E) {
  int i = blockIdx.x * 256 + threadIdx.x;
  if (i < N) off[i] = excl[i] + partial[i >> 8];
  if (i == N) off[N] = (unsigned)E;
}

// ---------------- CSR fill: atomic-free scatter ----------------
__global__ __launch_bounds__(256) void csr_fill_kernel(const int* __restrict__ src,
                                                       const int* __restrict__ dst,
                                                       const unsigned* __restrict__ rank,
                                                       const unsigned* __restrict__ off,
                                                       int* __restrict__ csr_src, int E) {
  int e = blockIdx.x * 256 + threadIdx.x;
  if (e >= E) return;
  csr_src[off[dst[e]] + rank[e]] = src[e];
}

// ---------------- gather body macro: wave-per-node aggregation into acc[8] ----------------
#define GATHER_BODY(TABLE)                                                       \
  const int node = (blockIdx.x * 256 + threadIdx.x) >> 6;                        \
  if (node >= N) return;                                                         \
  const int lane = threadIdx.x & 63;                                             \
  const int eslot = lane >> 4;                                                   \
  const int col = lane & 15;                                                     \
  const unsigned beg = off[node], end = off[node + 1];                           \
  const ushort* fbase = (TABLE) + col * 8;                                       \
  float acc[8];                                                                  \
  _Pragma("unroll") for (int t = 0; t < 8; ++t) acc[t] = 0.f;                    \
  auto accum = [&](int4 v) {                                                     \
    unsigned w0 = (unsigned)v.x, w1 = (unsigned)v.y;                             \
    unsigned w2 = (unsigned)v.z, w3 = (unsigned)v.w;                             \
    acc[0] += __uint_as_float(w0 << 16);                                         \
    acc[1] += __uint_as_float(w0 & 0xFFFF0000u);                                 \
    acc[2] += __uint_as_float(w1 << 16);                                         \
    acc[3] += __uint_as_float(w1 & 0xFFFF0000u);                                 \
    acc[4] += __uint_as_float(w2 << 16);                                         \
    acc[5] += __uint_as_float(w2 & 0xFFFF0000u);                                 \
    acc[6] += __uint_as_float(w3 << 16);                                         \
    acc[7] += __uint_as_float(w3 & 0xFFFF0000u);                                 \
  };                                                                             \
  unsigned base = beg;                                                           \
  for (; base + 16 <= end; base += 16) {                                         \
    int s0 = csr_src[base + eslot];                                              \
    int s1 = csr_src[base + 4 + eslot];                                          \
    int s2 = csr_src[base + 8 + eslot];                                          \
    int s3 = csr_src[base + 12 + eslot];                                         \
    int4 v0 = *(const int4*)(fbase + (size_t)s0 * DIM);                          \
    int4 v1 = *(const int4*)(fbase + (size_t)s1 * DIM);                          \
    int4 v2 = *(const int4*)(fbase + (size_t)s2 * DIM);                          \
    int4 v3 = *(const int4*)(fbase + (size_t)s3 * DIM);                          \
    accum(v0); accum(v1); accum(v2); accum(v3);                                  \
  }                                                                              \
  for (; base + 8 <= end; base += 8) {                                           \
    int s0 = csr_src[base + eslot];                                              \
    int s1 = csr_src[base + 4 + eslot];                                          \
    int4 v0 = *(const int4*)(fbase + (size_t)s0 * DIM);                          \
    int4 v1 = *(const int4*)(fbase + (size_t)s1 * DIM);                          \
    accum(v0); accum(v1);                                                        \
  }                                                                              \
  for (unsigned e = base + eslot; e < end; e += 4) {                             \
    int s = csr_src[e];                                                          \
    int4 v = *(const int4*)(fbase + (size_t)s * DIM);                            \
    accum(v);                                                                    \
  }                                                                              \
  _Pragma("unroll") for (int t = 0; t < 8; ++t) {                                \
    acc[t] += __shfl_xor(acc[t], 32, 64);                                        \
    acc[t] += __shfl_xor(acc[t], 16, 64);                                        \
  }

// ---------------- gather1: agg(xl), fused layer-1 epilogue -> h1 ----------------
__global__ __launch_bounds__(256) void gather1_kernel(
    const ushort* __restrict__ xl, const int* __restrict__ csr_src,
    const unsigned* __restrict__ off, const float* __restrict__ dinv,
    const ushort* __restrict__ xr, const float* __restrict__ b1,
    ushort* __restrict__ h1, int N) {
  GATHER_BODY(xl)
  if (eslot == 0) {
    float di = dinv[node];
    int4 xv = *(const int4*)(xr + (size_t)node * DIM + col * 8);
    float4 ba = *(const float4*)(b1 + col * 8);
    float4 bb = *(const float4*)(b1 + col * 8 + 4);
    unsigned w0 = (unsigned)xv.x, w1 = (unsigned)xv.y;
    unsigned w2 = (unsigned)xv.z, w3 = (unsigned)xv.w;
    float h[8];
    h[0] = fmaxf(acc[0] * di + __uint_as_float(w0 << 16) + ba.x, 0.f);
    h[1] = fmaxf(acc[1] * di + __uint_as_float(w0 & 0xFFFF0000u) + ba.y, 0.f);
    h[2] = fmaxf(acc[2] * di + __uint_as_float(w1 << 16) + ba.z, 0.f);
    h[3] = fmaxf(acc[3] * di + __uint_as_float(w1 & 0xFFFF0000u) + ba.w, 0.f);
    h[4] = fmaxf(acc[4] * di + __uint_as_float(w2 << 16) + bb.x, 0.f);
    h[5] = fmaxf(acc[5] * di + __uint_as_float(w2 & 0xFFFF0000u) + bb.y, 0.f);
    h[6] = fmaxf(acc[6] * di + __uint_as_float(w3 << 16) + bb.z, 0.f);
    h[7] = fmaxf(acc[7] * di + __uint_as_float(w3 & 0xFFFF0000u) + bb.w, 0.f);
    unsigned ph[4];
#pragma unroll
    for (int t = 0; t < 4; ++t)
      ph[t] = (unsigned)f2bf(h[2 * t]) | ((unsigned)f2bf(h[2 * t + 1]) << 16);
    *(int4*)(h1 + (size_t)node * DIM + col * 8) =
        make_int4((int)ph[0], (int)ph[1], (int)ph[2], (int)ph[3]);
  }
}

// ---------------- gather2: agg(h1) * dinv -> aggH bf16 ----------------
__global__ __launch_bounds__(256) void gather_wave_kernel(
    const ushort* __restrict__ featH, const int* __restrict__ csr_src,
    const unsigned* __restrict__ off, const float* __restrict__ dinv,
    ushort* __restrict__ aggH, int N) {
  GATHER_BODY(featH)
  if (eslot == 0) {
    float di = dinv[node];
    unsigned ph[4];
#pragma unroll
    for (int t = 0; t < 4; ++t) {
      ph[t] = (unsigned)f2bf(acc[2 * t] * di) | ((unsigned)f2bf(acc[2 * t + 1] * di) << 16);
    }
    *(int4*)(aggH + (size_t)node * DIM + col * 8) =
        make_int4((int)ph[0], (int)ph[1], (int)ph[2], (int)ph[3]);
  }
}

// ---------------- MFMA SAGE layer (layer 2 + fused lin3 -> y) ----------------
__global__ __launch_bounds__(256) void sage_mfma_kernel(
    const ushort* __restrict__ aggH, const ushort* xH,
    const ushort* __restrict__ WlH, const ushort* __restrict__ WrH,
    const float* __restrict__ bias,
    const float* __restrict__ W3l, const float* __restrict__ W3r,
    ushort* __restrict__ outH, float* __restrict__ y, int N) {
  __shared__ ushort As[128 * 64];  // 16 KB
  __shared__ ushort Bs[128 * 64];  // 16 KB

  const int tid = threadIdx.x;
  const int bm = blockIdx.x * 128;
  const int wave = tid >> 6;
  const int lane = tid & 63;
  const int l15 = lane & 15;
  const int quad = lane >> 4;
  const int wm = wave >> 1;
  const int wn = wave & 1;

  f32x4 acc[4][4];
#pragma unroll
  for (int i = 0; i < 4; ++i)
#pragma unroll
    for (int j = 0; j < 4; ++j) acc[i][j] = (f32x4){0.f, 0.f, 0.f, 0.f};

  for (int g = 0; g < 4; ++g) {
    const ushort* Ap = (g < 2) ? aggH : xH;
    const ushort* Wp = (g < 2) ? WlH : WrH;
    const int kt = (g & 1) << 6;
    __syncthreads();
#pragma unroll
    for (int c = 0; c < 4; ++c) {
      int flat = c * 256 + tid;
      int row = flat >> 3;
      int kg = flat & 7;
      int swz = (kg ^ (row & 7)) << 3;
      int grow = bm + row;
      if (grow >= N) grow = N - 1;
      *(int4*)(&As[row * 64 + swz]) = *(const int4*)(Ap + (size_t)grow * DIM + kt + kg * 8);
      *(int4*)(&Bs[row * 64 + swz]) = *(const int4*)(Wp + (size_t)row * DIM + kt + kg * 8);
    }
    __syncthreads();
#pragma unroll
    for (int ks = 0; ks < 2; ++ks) {
      bf16x8 af[4], bfr[4];
      int kg = (ks << 2) + quad;
#pragma unroll
      for (int i = 0; i < 4; ++i) {
        int ar = (wm << 6) + (i << 4) + l15;
        af[i] = *(const bf16x8*)(&As[ar * 64 + ((kg ^ (ar & 7)) << 3)]);
        int br = (wn << 6) + (i << 4) + l15;
        bfr[i] = *(const bf16x8*)(&Bs[br * 64 + ((kg ^ (br & 7)) << 3)]);
      }
#pragma unroll
      for (int i = 0; i < 4; ++i)
#pragma unroll
        for (int j = 0; j < 4; ++j)
          acc[i][j] = __builtin_amdgcn_mfma_f32_16x16x32_bf16(af[i], bfr[j], acc[i][j], 0, 0, 0);
    }
  }

  __syncthreads();  // As/Bs dead; alias epilogue buffers onto As
  float* WcF = reinterpret_cast<float*>(As);        // [128][4] = 2 KB
  float* YpF = reinterpret_cast<float*>(As) + 512;  // [128][4][2] = 4 KB

  if (W3l) {
    for (int t = tid; t < 512; t += 256) {
      int col = t >> 2, c = t & 3;
      WcF[t] = (c < 2) ? W3l[col * 2 + c] : W3r[col * 2 + (c - 2)];
    }
    __syncthreads();
  }

  float bv[4];
#pragma unroll
  for (int j = 0; j < 4; ++j) bv[j] = bias[(wn << 6) + (j << 4) + l15];

#pragma unroll
  for (int i = 0; i < 4; ++i) {
#pragma unroll
    for (int r = 0; r < 4; ++r) {
      const int rowl = (wm << 6) + (i << 4) + (quad << 2) + r;
      const int grow = bm + rowl;
      float p0 = 0.f, p1 = 0.f, p2 = 0.f, p3 = 0.f;
#pragma unroll
      for (int j = 0; j < 4; ++j) {
        int col = (wn << 6) + (j << 4) + l15;
        float v = fmaxf(acc[i][j][r] + bv[j], 0.f);
        ushort h = f2bf(v);
        if (outH && grow < N) outH[(size_t)grow * DIM + col] = h;
        if (W3l) {
          float qv = bf2f(h);
          p0 += qv * WcF[col * 4 + 0];
          p1 += qv * WcF[col * 4 + 1];
          p2 += qv * WcF[col * 4 + 2];
          p3 += qv * WcF[col * 4 + 3];
        }
      }
      if (W3l) {
#pragma unroll
        for (int o = 1; o < 16; o <<= 1) {
          p0 += __shfl_xor(p0, o, 64);
          p1 += __shfl_xor(p1, o, 64);
          p2 += __shfl_xor(p2, o, 64);
          p3 += __shfl_xor(p3, o, 64);
        }
        if (l15 == 0) {
          YpF[(rowl * 4 + 0) * 2 + wn] = p0;
          YpF[(rowl * 4 + 1) * 2 + wn] = p1;
          YpF[(rowl * 4 + 2) * 2 + wn] = p2;
          YpF[(rowl * 4 + 3) * 2 + wn] = p3;
        }
      }
    }
  }

  if (W3l) {
    __syncthreads();
    for (int t = tid; t < 512; t += 256) {
      int grow = bm + (t >> 2);
      if (grow < N) y[(size_t)grow * 4 + (t & 3)] = YpF[t * 2 + 0] + YpF[t * 2 + 1];
    }
  }
}

// ---------------- layer 3: 2-dim CSR gather + bias + relu + log_softmax ----------------
__global__ __launch_bounds__(256) void final3_kernel(const float* __restrict__ y,
                                                     const int* __restrict__ csr_src,
                                                     const unsigned* __restrict__ off,
                                                     const float* __restrict__ dinv,
                                                     const float* __restrict__ b3,
                                                     float* __restrict__ out, int N) {
  int n = blockIdx.x * 256 + threadIdx.x;
  if (n >= N) return;
  unsigned beg = off[n], end = off[n + 1];
  float s0 = 0.f, s1 = 0.f;
  for (unsigned e = beg; e < end; ++e) {
    int s = csr_src[e];
    float2 v = *reinterpret_cast<const float2*>(&y[(size_t)s * 4]);
    s0 += v.x; s1 += v.y;
  }
  float di = dinv[n];
  float o0 = fmaxf(s0 * di + y[(size_t)n * 4 + 2] + b3[0], 0.f);
  float o1 = fmaxf(s1 * di + y[(size_t)n * 4 + 3] + b3[1], 0.f);
  float m = fmaxf(o0, o1);
  float l = m + logf(expf(o0 - m) + expf(o1 - m));
  out[n * 2 + 0] = o0 - l;
  out[n * 2 + 1] = o1 - l;
}

extern "C" void kernel_launch(void* const* d_in, const int* in_sizes, int n_in,
                              void* d_out, int out_size, void* d_ws, size_t ws_size,
                              hipStream_t stream) {
  const float* x   = (const float*)d_in[0];
  const int*   ei  = (const int*)d_in[1];
  const float* W1l = (const float*)d_in[2];
  const float* W1r = (const float*)d_in[3];
  const float* b1  = (const float*)d_in[4];
  const float* W2l = (const float*)d_in[5];
  const float* W2r = (const float*)d_in[6];
  const float* b2  = (const float*)d_in[7];
  const float* W3l = (const float*)d_in[8];
  const float* W3r = (const float*)d_in[9];
  const float* b3  = (const float*)d_in[10];

  const int N = in_sizes[0] / DIM;  // 100000
  const int E = in_sizes[1] / 2;    // 1600000
  const int* src = ei;
  const int* dst = ei + E;
  const int B = (N + 255) / 256;

  char* ws = (char*)d_ws;
  size_t off_b = 0;
  auto alloc = [&](size_t bytes) {
    void* p = ws + off_b;
    off_b = (off_b + bytes + 255) & ~(size_t)255;
    return p;
  };
  unsigned* deg     = (unsigned*)alloc((size_t)N * 4);
  unsigned* excl    = (unsigned*)alloc((size_t)N * 4);
  unsigned* partial = (unsigned*)alloc((size_t)B * 4);
  unsigned* offs    = (unsigned*)alloc((size_t)(N + 1) * 4);
  unsigned* rank    = (unsigned*)alloc((size_t)E * 4);
  int*      csr_src = (int*)alloc((size_t)E * 4);
  float*    dinv    = (float*)alloc((size_t)N * 4);
  ushort*   xl      = (ushort*)alloc((size_t)N * DIM * 2);
  ushort*   xr      = (ushort*)alloc((size_t)N * DIM * 2);
  ushort*   h1      = (ushort*)alloc((size_t)N * DIM * 2);
  ushort*   tabs    = (ushort*)alloc((size_t)2 * 16384 * 2);
  float*    y       = (float*)alloc((size_t)N * 4 * 4);
  // aggH aliases xl: xl last read by gather1; aggH written strictly afterwards.
  ushort* aggH = xl;

  const int H   = (E + 255) / 256;  // 6250 hist tiles
  const int G64 = (N + 63) / 64;    // 1563 gemm row tiles
  const int AUXN = G64 + 128;       // gemm + wsplit
  const int HQ = (H + 3) / 4;       // 1563
  const int P = (AUXN > HQ) ? AUXN : HQ;  // 1691

  hipMemsetAsync(deg, 0, (size_t)N * 4, stream);
  // K1: hist atomics (floor) || byte-minimal layer-1 GEMMs || W2 wsplit
  prep6_kernel<<<5 * P, 256, 0, stream>>>(dst, deg, rank, E, x, W1l, W1r, xl, xr,
                                          W2l, W2r, tabs, H, G64, N);
  // scan chain
  scan_block_kernel<<<B, 256, 0, stream>>>(deg, excl, partial, dinv, N);
  scan_partials_kernel<<<1, 256, 0, stream>>>(partial, B);
  add_offsets_kernel<<<(N + 256) / 256, 256, 0, stream>>>(excl, partial, offs, N, E);
  // CSR fill
  csr_fill_kernel<<<H, 256, 0, stream>>>(src, dst, rank, offs, csr_src, E);

  const ushort* W2lH = tabs;
  const ushort* W2rH = tabs + 16384;
  const int G = (N + 127) / 128;
  const int gather_grid = (N + 3) / 4;  // one wave per node

  // layer 1: h1 = relu(mean_agg(xl) + xr + b1)
  gather1_kernel<<<gather_grid, 256, 0, stream>>>(xl, csr_src, offs, dinv, xr, b1, h1, N);
  // layer 2: agg2 = mean_agg(h1); y = lin3(relu(agg2@W2l + h1@W2r + b2))
  gather_wave_kernel<<<gather_grid, 256, 0, stream>>>(h1, csr_src, offs, dinv, aggH, N);
  sage_mfma_kernel<<<G, 256, 0, stream>>>(aggH, h1, W2lH, W2rH, b2,
                                          W3l, W3r, nullptr, y, N);
  // layer 3
  final3_kernel<<<(N + 255) / 256, 256, 0, stream>>>(y, csr_src, offs, dinv, b3, (float*)d_out, N);
}

// Round 7
// 360.368 us; speedup vs baseline: 1.5234x; 1.5234x over previous
//
#include <hip/hip_runtime.h>
#include <math.h>

#define DIM 128

typedef __attribute__((ext_vector_type(8))) short bf16x8;
typedef __attribute__((ext_vector_type(4))) float f32x4;

__device__ __forceinline__ ushort f2bf(float f) {  // RTNE
  unsigned u = __float_as_uint(f);
  return (ushort)((u + 0x7FFFu + ((u >> 16) & 1u)) >> 16);
}
__device__ __forceinline__ float bf2f(ushort h) {
  return __uint_as_float(((unsigned)h) << 16);
}

// ================= CSR build via bucketed counting sort (NO global atomics) =================
// bucket = dst >> 7 (128 nodes/bucket). Aggregation is order-independent -> unstable
// binning is fine, rank[] deleted, hist-atomic stream (55us floor + ~50MB phantom
// write traffic) and csr_fill's full-random 4B scatter (~100MB write-allocate) deleted.

// ---- K_A: per-block bucket histogram || x->bf16 cast || W1/W2 wsplit ----
__global__ __launch_bounds__(256) void count_cast_kernel(
    const int* __restrict__ dst, unsigned* __restrict__ counts, int E, int NB, int NBUCK,
    const float* __restrict__ x, ushort* __restrict__ xh, long total_f,
    const float* __restrict__ W1l, const float* __restrict__ W1r,
    const float* __restrict__ W2l, const float* __restrict__ W2r,
    ushort* __restrict__ tabs, int CB) {
  __shared__ unsigned hist[1024];
  const int tid = threadIdx.x;
  int bid = blockIdx.x;
  if (bid < NB) {  // count role: 2048 edges per block
    for (int i = tid; i < NBUCK; i += 256) hist[i] = 0u;
    __syncthreads();
    long base = (long)bid * 2048;
#pragma unroll
    for (int c = 0; c < 8; ++c) {
      long e = base + c * 256 + tid;
      if (e < E) atomicAdd(&hist[((unsigned)dst[e]) >> 7], 1u);
    }
    __syncthreads();
    for (int i = tid; i < NBUCK; i += 256)
      counts[(size_t)bid * NBUCK + i] = hist[i];
    return;
  }
  int aid = bid - NB;
  if (aid < CB) {  // cast role: 2048 float4 per block
    long i = ((long)aid * 2048 + tid) * 4;
    for (int c = 0; c < 8; ++c, i += 1024) {
      if (i >= total_f) break;
      float4 v = *(const float4*)(x + i);
      uint2 Hh;
      Hh.x = (unsigned)f2bf(v.x) | ((unsigned)f2bf(v.y) << 16);
      Hh.y = (unsigned)f2bf(v.z) | ((unsigned)f2bf(v.w) << 16);
      *(uint2*)(xh + i) = Hh;
    }
    return;
  }
  int aid2 = aid - CB;  // wsplit role: 256 blocks, 4 mats transposed+cast
  if (aid2 < 256) {
    int m = aid2 >> 6;
    const float* W = (m == 0) ? W1l : (m == 1) ? W1r : (m == 2) ? W2l : W2r;
    ushort* Ht = tabs + (size_t)m * 16384;
    int idx = (aid2 & 63) * 256 + tid;
    int k = idx >> 7, n = idx & 127;
    Ht[n * DIM + k] = f2bf(W[idx]);
  }
}

// ---- K_B: per-bucket column scan of counts[block][bucket] (one wave per bucket) ----
__global__ __launch_bounds__(256) void colscan_kernel(unsigned* __restrict__ counts,
                                                      unsigned* __restrict__ totals,
                                                      int NB, int NBUCK) {
  int wid = (blockIdx.x << 2) + (threadIdx.x >> 6);
  int lane = threadIdx.x & 63;
  if (wid >= NBUCK) return;
  unsigned carry = 0u;
  for (int k0 = 0; k0 < NB; k0 += 64) {
    int k = k0 + lane;
    unsigned v = (k < NB) ? counts[(size_t)k * NBUCK + wid] : 0u;
    unsigned s = v;
#pragma unroll
    for (int o = 1; o < 64; o <<= 1) {
      unsigned t = __shfl_up(s, o, 64);
      if (lane >= o) s += t;
    }
    if (k < NB) counts[(size_t)k * NBUCK + wid] = carry + s - v;  // exclusive
    carry += __shfl(s, 63, 64);
  }
  if (lane == 0) totals[wid] = carry;
}

// ---- K_C: scan bucket totals -> bucket bases; totals[NBUCK] = E ----
__global__ __launch_bounds__(256) void totscan_kernel(unsigned* __restrict__ totals,
                                                      int NBUCK, int E) {
  __shared__ unsigned s[256];
  __shared__ unsigned carry;
  if (threadIdx.x == 0) carry = 0u;
  __syncthreads();
  for (int base = 0; base < NBUCK; base += 256) {
    int i = base + threadIdx.x;
    unsigned v = (i < NBUCK) ? totals[i] : 0u;
    s[threadIdx.x] = v;
    __syncthreads();
#pragma unroll
    for (int d = 1; d < 256; d <<= 1) {
      unsigned t = (threadIdx.x >= d) ? s[threadIdx.x - d] : 0u;
      __syncthreads();
      s[threadIdx.x] += t;
      __syncthreads();
    }
    if (i < NBUCK) totals[i] = carry + s[threadIdx.x] - v;
    __syncthreads();
    if (threadIdx.x == 0) carry += s[255];
    __syncthreads();
  }
  if (threadIdx.x == 0) totals[NBUCK] = (unsigned)E;
}

// ---- K_D: scatter (src,dst) pairs into bucket-grouped order (LDS cursors) ----
__global__ __launch_bounds__(256) void cscatter_kernel(
    const int* __restrict__ src, const int* __restrict__ dst,
    const unsigned* __restrict__ counts, const unsigned* __restrict__ totals,
    uint2* __restrict__ pairs, int E, int NBUCK) {
  __shared__ unsigned basec[1024];
  const int tid = threadIdx.x;
  const int bid = blockIdx.x;
  for (int i = tid; i < NBUCK; i += 256)
    basec[i] = counts[(size_t)bid * NBUCK + i] + totals[i];
  __syncthreads();
  long base = (long)bid * 2048;
#pragma unroll
  for (int c = 0; c < 8; ++c) {
    long e = base + c * 256 + tid;
    if (e < E) {
      int d = dst[e];
      unsigned pos = atomicAdd(&basec[((unsigned)d) >> 7], 1u);
      pairs[pos] = make_uint2((unsigned)src[e], (unsigned)d);
    }
  }
}

// ---- K_E: per-bucket fine binning -> csr_src (L2 window), offs, dinv ----
__global__ __launch_bounds__(256) void fine_kernel(
    const uint2* __restrict__ pairs, const unsigned* __restrict__ totals,
    int* __restrict__ csr_src, unsigned* __restrict__ offs, float* __restrict__ dinv,
    int N, int NBUCK, int E) {
  __shared__ int lsrc[4096];
  __shared__ ushort ldst[4096];
  __shared__ unsigned hist[128], excl[128], cur[128];
  const int tid = threadIdx.x;
  const int b = blockIdx.x;
  const unsigned t0 = totals[b], t1 = totals[b + 1];
  unsigned cnt = t1 - t0;
  if (cnt > 4096u) cnt = 4096u;  // Poisson(2048): statistically impossible
  if (tid < 128) { hist[tid] = 0u; cur[tid] = 0u; }
  __syncthreads();
  for (unsigned i = tid; i < cnt; i += 256) {
    uint2 p = pairs[t0 + i];
    lsrc[i] = (int)p.x;
    int nl = (int)(p.y & 127u);
    ldst[i] = (ushort)nl;
    atomicAdd(&hist[nl], 1u);
  }
  __syncthreads();
  if (tid < 64) {  // exclusive scan of 128 bins (one wave, 2 chunks)
    unsigned v0 = hist[tid], v1 = hist[tid + 64];
    unsigned s0 = v0, s1 = v1;
#pragma unroll
    for (int o = 1; o < 64; o <<= 1) {
      unsigned u0 = __shfl_up(s0, o, 64);
      unsigned u1 = __shfl_up(s1, o, 64);
      if (tid >= o) { s0 += u0; s1 += u1; }
    }
    unsigned tot0 = __shfl(s0, 63, 64);
    excl[tid] = s0 - v0;
    excl[tid + 64] = tot0 + s1 - v1;
  }
  __syncthreads();
  if (tid < 128) {
    int node = (b << 7) + tid;
    if (node < N) {
      offs[node] = t0 + excl[tid];
      dinv[node] = 1.0f / fmaxf((float)hist[tid], 1.0f);
    }
  }
  if (b == 0 && tid == 255) offs[N] = (unsigned)E;
  for (unsigned i = tid; i < cnt; i += 256) {
    int nl = (int)ldst[i];
    unsigned slot = excl[nl] + atomicAdd(&cur[nl], 1u);
    csr_src[t0 + slot] = lsrc[i];  // 16KB window -> L2 write-combined
  }
}

// ================= downstream: R0's proven kernels, verbatim =================

#define GATHER_BODY(TABLE)                                                       \
  const int node = (blockIdx.x * 256 + threadIdx.x) >> 6;                        \
  if (node >= N) return;                                                         \
  const int lane = threadIdx.x & 63;                                             \
  const int eslot = lane >> 4;                                                   \
  const int col = lane & 15;                                                     \
  const unsigned beg = off[node], end = off[node + 1];                           \
  const ushort* fbase = (TABLE) + col * 8;                                       \
  float acc[8];                                                                  \
  _Pragma("unroll") for (int t = 0; t < 8; ++t) acc[t] = 0.f;                    \
  auto accum = [&](int4 v) {                                                     \
    unsigned w0 = (unsigned)v.x, w1 = (unsigned)v.y;                             \
    unsigned w2 = (unsigned)v.z, w3 = (unsigned)v.w;                             \
    acc[0] += __uint_as_float(w0 << 16);                                         \
    acc[1] += __uint_as_float(w0 & 0xFFFF0000u);                                 \
    acc[2] += __uint_as_float(w1 << 16);                                         \
    acc[3] += __uint_as_float(w1 & 0xFFFF0000u);                                 \
    acc[4] += __uint_as_float(w2 << 16);                                         \
    acc[5] += __uint_as_float(w2 & 0xFFFF0000u);                                 \
    acc[6] += __uint_as_float(w3 << 16);                                         \
    acc[7] += __uint_as_float(w3 & 0xFFFF0000u);                                 \
  };                                                                             \
  unsigned base = beg;                                                           \
  for (; base + 16 <= end; base += 16) {                                         \
    int s0 = csr_src[base + eslot];                                              \
    int s1 = csr_src[base + 4 + eslot];                                          \
    int s2 = csr_src[base + 8 + eslot];                                          \
    int s3 = csr_src[base + 12 + eslot];                                         \
    int4 v0 = *(const int4*)(fbase + (size_t)s0 * DIM);                          \
    int4 v1 = *(const int4*)(fbase + (size_t)s1 * DIM);                          \
    int4 v2 = *(const int4*)(fbase + (size_t)s2 * DIM);                          \
    int4 v3 = *(const int4*)(fbase + (size_t)s3 * DIM);                          \
    accum(v0); accum(v1); accum(v2); accum(v3);                                  \
  }                                                                              \
  for (; base + 8 <= end; base += 8) {                                           \
    int s0 = csr_src[base + eslot];                                              \
    int s1 = csr_src[base + 4 + eslot];                                          \
    int4 v0 = *(const int4*)(fbase + (size_t)s0 * DIM);                          \
    int4 v1 = *(const int4*)(fbase + (size_t)s1 * DIM);                          \
    accum(v0); accum(v1);                                                        \
  }                                                                              \
  for (unsigned e = base + eslot; e < end; e += 4) {                             \
    int s = csr_src[e];                                                          \
    int4 v = *(const int4*)(fbase + (size_t)s * DIM);                            \
    accum(v);                                                                    \
  }                                                                              \
  _Pragma("unroll") for (int t = 0; t < 8; ++t) {                                \
    acc[t] += __shfl_xor(acc[t], 32, 64);                                        \
    acc[t] += __shfl_xor(acc[t], 16, 64);                                        \
  }

__global__ __launch_bounds__(256) void gather_wave_kernel(
    const ushort* __restrict__ featH, const int* __restrict__ csr_src,
    const unsigned* __restrict__ off, const float* __restrict__ dinv,
    ushort* __restrict__ aggH, int N) {
  GATHER_BODY(featH)
  if (eslot == 0) {
    float di = dinv[node];
    unsigned ph[4];
#pragma unroll
    for (int t = 0; t < 4; ++t) {
      ph[t] = (unsigned)f2bf(acc[2 * t] * di) | ((unsigned)f2bf(acc[2 * t + 1] * di) << 16);
    }
    *(int4*)(aggH + (size_t)node * DIM + col * 8) =
        make_int4((int)ph[0], (int)ph[1], (int)ph[2], (int)ph[3]);
  }
}

__global__ __launch_bounds__(256) void sage_mfma_kernel(
    const ushort* __restrict__ aggH, const ushort* xH,
    const ushort* __restrict__ WlH, const ushort* __restrict__ WrH,
    const float* __restrict__ bias,
    const float* __restrict__ W3l, const float* __restrict__ W3r,
    ushort* __restrict__ outH, float* __restrict__ y, int N) {
  __shared__ ushort As[128 * 64];  // 16 KB
  __shared__ ushort Bs[128 * 64];  // 16 KB

  const int tid = threadIdx.x;
  const int bm = blockIdx.x * 128;
  const int wave = tid >> 6;
  const int lane = tid & 63;
  const int l15 = lane & 15;
  const int quad = lane >> 4;
  const int wm = wave >> 1;
  const int wn = wave & 1;

  f32x4 acc[4][4];
#pragma unroll
  for (int i = 0; i < 4; ++i)
#pragma unroll
    for (int j = 0; j < 4; ++j) acc[i][j] = (f32x4){0.f, 0.f, 0.f, 0.f};

  for (int g = 0; g < 4; ++g) {
    const ushort* Ap = (g < 2) ? aggH : xH;
    const ushort* Wp = (g < 2) ? WlH : WrH;
    const int kt = (g & 1) << 6;
    __syncthreads();
#pragma unroll
    for (int c = 0; c < 4; ++c) {
      int flat = c * 256 + tid;
      int row = flat >> 3;
      int kg = flat & 7;
      int swz = (kg ^ (row & 7)) << 3;
      int grow = bm + row;
      if (grow >= N) grow = N - 1;
      *(int4*)(&As[row * 64 + swz]) = *(const int4*)(Ap + (size_t)grow * DIM + kt + kg * 8);
      *(int4*)(&Bs[row * 64 + swz]) = *(const int4*)(Wp + (size_t)row * DIM + kt + kg * 8);
    }
    __syncthreads();
#pragma unroll
    for (int ks = 0; ks < 2; ++ks) {
      bf16x8 af[4], bfr[4];
      int kg = (ks << 2) + quad;
#pragma unroll
      for (int i = 0; i < 4; ++i) {
        int ar = (wm << 6) + (i << 4) + l15;
        af[i] = *(const bf16x8*)(&As[ar * 64 + ((kg ^ (ar & 7)) << 3)]);
        int br = (wn << 6) + (i << 4) + l15;
        bfr[i] = *(const bf16x8*)(&Bs[br * 64 + ((kg ^ (br & 7)) << 3)]);
      }
#pragma unroll
      for (int i = 0; i < 4; ++i)
#pragma unroll
        for (int j = 0; j < 4; ++j)
          acc[i][j] = __builtin_amdgcn_mfma_f32_16x16x32_bf16(af[i], bfr[j], acc[i][j], 0, 0, 0);
    }
  }

  __syncthreads();  // As/Bs dead; alias epilogue buffers onto As
  float* WcF = reinterpret_cast<float*>(As);        // [128][4] = 2 KB
  float* YpF = reinterpret_cast<float*>(As) + 512;  // [128][4][2] = 4 KB

  if (W3l) {
    for (int t = tid; t < 512; t += 256) {
      int col = t >> 2, c = t & 3;
      WcF[t] = (c < 2) ? W3l[col * 2 + c] : W3r[col * 2 + (c - 2)];
    }
    __syncthreads();
  }

  float bv[4];
#pragma unroll
  for (int j = 0; j < 4; ++j) bv[j] = bias[(wn << 6) + (j << 4) + l15];

#pragma unroll
  for (int i = 0; i < 4; ++i) {
#pragma unroll
    for (int r = 0; r < 4; ++r) {
      const int rowl = (wm << 6) + (i << 4) + (quad << 2) + r;
      const int grow = bm + rowl;
      float p0 = 0.f, p1 = 0.f, p2 = 0.f, p3 = 0.f;
#pragma unroll
      for (int j = 0; j < 4; ++j) {
        int col = (wn << 6) + (j << 4) + l15;
        float v = fmaxf(acc[i][j][r] + bv[j], 0.f);
        ushort h = f2bf(v);
        if (outH && grow < N) outH[(size_t)grow * DIM + col] = h;
        if (W3l) {
          float qv = bf2f(h);
          p0 += qv * WcF[col * 4 + 0];
          p1 += qv * WcF[col * 4 + 1];
          p2 += qv * WcF[col * 4 + 2];
          p3 += qv * WcF[col * 4 + 3];
        }
      }
      if (W3l) {
#pragma unroll
        for (int o = 1; o < 16; o <<= 1) {
          p0 += __shfl_xor(p0, o, 64);
          p1 += __shfl_xor(p1, o, 64);
          p2 += __shfl_xor(p2, o, 64);
          p3 += __shfl_xor(p3, o, 64);
        }
        if (l15 == 0) {
          YpF[(rowl * 4 + 0) * 2 + wn] = p0;
          YpF[(rowl * 4 + 1) * 2 + wn] = p1;
          YpF[(rowl * 4 + 2) * 2 + wn] = p2;
          YpF[(rowl * 4 + 3) * 2 + wn] = p3;
        }
      }
    }
  }

  if (W3l) {
    __syncthreads();
    for (int t = tid; t < 512; t += 256) {
      int grow = bm + (t >> 2);
      if (grow < N) y[(size_t)grow * 4 + (t & 3)] = YpF[t * 2 + 0] + YpF[t * 2 + 1];
    }
  }
}

__global__ __launch_bounds__(256) void final3_kernel(const float* __restrict__ y,
                                                     const int* __restrict__ csr_src,
                                                     const unsigned* __restrict__ off,
                                                     const float* __restrict__ dinv,
                                                     const float* __restrict__ b3,
                                                     float* __restrict__ out, int N) {
  int n = blockIdx.x * 256 + threadIdx.x;
  if (n >= N) return;
  unsigned beg = off[n], end = off[n + 1];
  float s0 = 0.f, s1 = 0.f;
  for (unsigned e = beg; e < end; ++e) {
    int s = csr_src[e];
    float2 v = *reinterpret_cast<const float2*>(&y[(size_t)s * 4]);
    s0 += v.x; s1 += v.y;
  }
  float di = dinv[n];
  float o0 = fmaxf(s0 * di + y[(size_t)n * 4 + 2] + b3[0], 0.f);
  float o1 = fmaxf(s1 * di + y[(size_t)n * 4 + 3] + b3[1], 0.f);
  float m = fmaxf(o0, o1);
  float l = m + logf(expf(o0 - m) + expf(o1 - m));
  out[n * 2 + 0] = o0 - l;
  out[n * 2 + 1] = o1 - l;
}

extern "C" void kernel_launch(void* const* d_in, const int* in_sizes, int n_in,
                              void* d_out, int out_size, void* d_ws, size_t ws_size,
                              hipStream_t stream) {
  const float* x   = (const float*)d_in[0];
  const int*   ei  = (const int*)d_in[1];
  const float* W1l = (const float*)d_in[2];
  const float* W1r = (const float*)d_in[3];
  const float* b1  = (const float*)d_in[4];
  const float* W2l = (const float*)d_in[5];
  const float* W2r = (const float*)d_in[6];
  const float* b2  = (const float*)d_in[7];
  const float* W3l = (const float*)d_in[8];
  const float* W3r = (const float*)d_in[9];
  const float* b3  = (const float*)d_in[10];

  const int N = in_sizes[0] / DIM;  // 100000
  const int E = in_sizes[1] / 2;    // 1600000
  const int* src = ei;
  const int* dst = ei + E;

  const int NBUCK = (N + 127) >> 7;            // 782 buckets (128 nodes each)
  const int NB    = (E + 2047) / 2048;         // 782 count/scatter blocks
  const long total_f = (long)N * DIM;
  const int CB    = (int)((total_f / 4 + 2047) / 2048);  // 1563 cast blocks

  char* ws = (char*)d_ws;
  size_t off_b = 0;
  auto alloc = [&](size_t bytes) {
    void* p = ws + off_b;
    off_b = (off_b + bytes + 255) & ~(size_t)255;
    return p;
  };
  unsigned* counts  = (unsigned*)alloc((size_t)NB * NBUCK * 4);  // 2.45 MB
  unsigned* totals  = (unsigned*)alloc((size_t)(NBUCK + 1) * 4);
  // pairs (12.8 MB) and aggH (25.6 MB) share one region: pairs last read in fine_kernel,
  // aggH first written by gather_wave strictly afterwards.
  void*     shared_ = alloc((size_t)N * DIM * 2);
  uint2*    pairs   = (uint2*)shared_;
  ushort*   aggH    = (ushort*)shared_;
  int*      csr_src = (int*)alloc((size_t)E * 4);
  unsigned* offs    = (unsigned*)alloc((size_t)(N + 1) * 4);
  float*    dinv    = (float*)alloc((size_t)N * 4);
  ushort*   xh      = (ushort*)alloc((size_t)N * DIM * 2);
  ushort*   tabs    = (ushort*)alloc((size_t)4 * 16384 * 2);
  float*    y       = (float*)alloc((size_t)N * 4 * 4);
  // total ~ 63 MB

  // ---- CSR build (no global atomics, no memset) ----
  count_cast_kernel<<<NB + CB + 256, 256, 0, stream>>>(
      dst, counts, E, NB, NBUCK, x, xh, total_f, W1l, W1r, W2l, W2r, tabs, CB);
  colscan_kernel<<<(NBUCK + 3) / 4, 256, 0, stream>>>(counts, totals, NB, NBUCK);
  totscan_kernel<<<1, 256, 0, stream>>>(totals, NBUCK, E);
  cscatter_kernel<<<NB, 256, 0, stream>>>(src, dst, counts, totals, pairs, E, NBUCK);
  fine_kernel<<<NBUCK, 256, 0, stream>>>(pairs, totals, csr_src, offs, dinv, N, NBUCK, E);

  const ushort* W1lH = tabs;
  const ushort* W1rH = tabs + 16384;
  const ushort* W2lH = tabs + 32768;
  const ushort* W2rH = tabs + 49152;
  const int G = (N + 127) / 128;
  const int gather_grid = (N + 3) / 4;  // one wave per node

  // ---- layer 1: h1 = relu(agg@W1l + x@W1r + b1), in-place over xh ----
  gather_wave_kernel<<<gather_grid, 256, 0, stream>>>(xh, csr_src, offs, dinv, aggH, N);
  sage_mfma_kernel<<<G, 256, 0, stream>>>(aggH, xh, W1lH, W1rH, b1,
                                          nullptr, nullptr, xh, nullptr, N);
  // ---- layer 2 + fused lin3 -> y ----
  gather_wave_kernel<<<gather_grid, 256, 0, stream>>>(xh, csr_src, offs, dinv, aggH, N);
  sage_mfma_kernel<<<G, 256, 0, stream>>>(aggH, xh, W2lH, W2rH, b2,
                                          W3l, W3r, nullptr, y, N);
  // ---- layer 3 ----
  final3_kernel<<<(N + 255) / 256, 256, 0, stream>>>(y, csr_src, offs, dinv, b3, (float*)d_out, N);
}

// Round 8
// 353.672 us; speedup vs baseline: 1.5523x; 1.0189x over previous
//
#include <hip/hip_runtime.h>
#include <math.h>

#define DIM 128

typedef __attribute__((ext_vector_type(8))) short bf16x8;
typedef __attribute__((ext_vector_type(4))) float f32x4;

__device__ __forceinline__ ushort f2bf(float f) {  // RTNE
  unsigned u = __float_as_uint(f);
  return (ushort)((u + 0x7FFFu + ((u >> 16) & 1u)) >> 16);
}
__device__ __forceinline__ float bf2f(ushort h) {
  return __uint_as_float(((unsigned)h) << 16);
}

// ================= CSR build via bucketed counting sort (NO global atomics) =================
// bucket = dst >> 7 (128 nodes/bucket); unstable binning (aggregation order-free).

// ---- K_A: per-block bucket histogram || x->bf16 cast || W1/W2 wsplit ----
__global__ __launch_bounds__(256) void count_cast_kernel(
    const int* __restrict__ dst, unsigned* __restrict__ counts, int E, int NB, int NBUCK,
    const float* __restrict__ x, ushort* __restrict__ xh, long total_f,
    const float* __restrict__ W1l, const float* __restrict__ W1r,
    const float* __restrict__ W2l, const float* __restrict__ W2r,
    ushort* __restrict__ tabs, int CB) {
  __shared__ unsigned hist[1024];
  const int tid = threadIdx.x;
  int bid = blockIdx.x;
  if (bid < NB) {  // count role: 2048 edges per block
    for (int i = tid; i < NBUCK; i += 256) hist[i] = 0u;
    __syncthreads();
    long base = (long)bid * 2048;
#pragma unroll
    for (int c = 0; c < 8; ++c) {
      long e = base + c * 256 + tid;
      if (e < E) atomicAdd(&hist[((unsigned)dst[e]) >> 7], 1u);
    }
    __syncthreads();
    for (int i = tid; i < NBUCK; i += 256)
      counts[(size_t)bid * NBUCK + i] = hist[i];
    return;
  }
  int aid = bid - NB;
  if (aid < CB) {  // cast role: 2048 float4 per block
    long i = ((long)aid * 2048 + tid) * 4;
    for (int c = 0; c < 8; ++c, i += 1024) {
      if (i >= total_f) break;
      float4 v = *(const float4*)(x + i);
      uint2 Hh;
      Hh.x = (unsigned)f2bf(v.x) | ((unsigned)f2bf(v.y) << 16);
      Hh.y = (unsigned)f2bf(v.z) | ((unsigned)f2bf(v.w) << 16);
      *(uint2*)(xh + i) = Hh;
    }
    return;
  }
  int aid2 = aid - CB;  // wsplit role: 256 blocks, 4 mats transposed+cast
  if (aid2 < 256) {
    int m = aid2 >> 6;
    const float* W = (m == 0) ? W1l : (m == 1) ? W1r : (m == 2) ? W2l : W2r;
    ushort* Ht = tabs + (size_t)m * 16384;
    int idx = (aid2 & 63) * 256 + tid;
    int k = idx >> 7, n = idx & 127;
    Ht[n * DIM + k] = f2bf(W[idx]);
  }
}

// ---- K_B: per-bucket column scan of counts[block][bucket] (one wave per bucket) ----
__global__ __launch_bounds__(256) void colscan_kernel(unsigned* __restrict__ counts,
                                                      unsigned* __restrict__ totals,
                                                      int NB, int NBUCK) {
  int wid = (blockIdx.x << 2) + (threadIdx.x >> 6);
  int lane = threadIdx.x & 63;
  if (wid >= NBUCK) return;
  unsigned carry = 0u;
  for (int k0 = 0; k0 < NB; k0 += 64) {
    int k = k0 + lane;
    unsigned v = (k < NB) ? counts[(size_t)k * NBUCK + wid] : 0u;
    unsigned s = v;
#pragma unroll
    for (int o = 1; o < 64; o <<= 1) {
      unsigned t = __shfl_up(s, o, 64);
      if (lane >= o) s += t;
    }
    if (k < NB) counts[(size_t)k * NBUCK + wid] = carry + s - v;  // exclusive
    carry += __shfl(s, 63, 64);
  }
  if (lane == 0) totals[wid] = carry;
}

// ---- K_C: scan bucket totals -> bucket bases; totals[NBUCK] = E ----
__global__ __launch_bounds__(256) void totscan_kernel(unsigned* __restrict__ totals,
                                                      int NBUCK, int E) {
  __shared__ unsigned s[256];
  __shared__ unsigned carry;
  if (threadIdx.x == 0) carry = 0u;
  __syncthreads();
  for (int base = 0; base < NBUCK; base += 256) {
    int i = base + threadIdx.x;
    unsigned v = (i < NBUCK) ? totals[i] : 0u;
    s[threadIdx.x] = v;
    __syncthreads();
#pragma unroll
    for (int d = 1; d < 256; d <<= 1) {
      unsigned t = (threadIdx.x >= d) ? s[threadIdx.x - d] : 0u;
      __syncthreads();
      s[threadIdx.x] += t;
      __syncthreads();
    }
    if (i < NBUCK) totals[i] = carry + s[threadIdx.x] - v;
    __syncthreads();
    if (threadIdx.x == 0) carry += s[255];
    __syncthreads();
  }
  if (threadIdx.x == 0) totals[NBUCK] = (unsigned)E;
}

// ---- K_D: scatter PACKED (src<<7 | dst&127) u32 into bucket-grouped order ----
// src < 2^17 (N=100000), local dst 7 bits -> 24 bits; halves pairs traffic vs uint2.
__global__ __launch_bounds__(256) void cscatter_kernel(
    const int* __restrict__ src, const int* __restrict__ dst,
    const unsigned* __restrict__ counts, const unsigned* __restrict__ totals,
    unsigned* __restrict__ pairs, int E, int NBUCK) {
  __shared__ unsigned basec[1024];
  const int tid = threadIdx.x;
  const int bid = blockIdx.x;
  for (int i = tid; i < NBUCK; i += 256)
    basec[i] = counts[(size_t)bid * NBUCK + i] + totals[i];
  __syncthreads();
  long base = (long)bid * 2048;
#pragma unroll
  for (int c = 0; c < 8; ++c) {
    long e = base + c * 256 + tid;
    if (e < E) {
      unsigned d = (unsigned)dst[e];
      unsigned pos = atomicAdd(&basec[d >> 7], 1u);
      pairs[pos] = ((unsigned)src[e] << 7) | (d & 127u);
    }
  }
}

// ---- K_E: per-bucket fine binning -> csr_src, offs, dinv ----
__global__ __launch_bounds__(256) void fine_kernel(
    const unsigned* __restrict__ pairs, const unsigned* __restrict__ totals,
    int* __restrict__ csr_src, unsigned* __restrict__ offs, float* __restrict__ dinv,
    int N, int NBUCK, int E) {
  __shared__ int lsrc[4096];
  __shared__ ushort ldst[4096];
  __shared__ unsigned hist[128], excl[128], cur[128];
  const int tid = threadIdx.x;
  const int b = blockIdx.x;
  const unsigned t0 = totals[b], t1 = totals[b + 1];
  unsigned cnt = t1 - t0;
  if (cnt > 4096u) cnt = 4096u;  // Poisson(2048): statistically impossible
  if (tid < 128) { hist[tid] = 0u; cur[tid] = 0u; }
  __syncthreads();
  for (unsigned i = tid; i < cnt; i += 256) {
    unsigned p = pairs[t0 + i];
    lsrc[i] = (int)(p >> 7);
    int nl = (int)(p & 127u);
    ldst[i] = (ushort)nl;
    atomicAdd(&hist[nl], 1u);
  }
  __syncthreads();
  if (tid < 64) {  // exclusive scan of 128 bins (one wave, 2 chunks)
    unsigned v0 = hist[tid], v1 = hist[tid + 64];
    unsigned s0 = v0, s1 = v1;
#pragma unroll
    for (int o = 1; o < 64; o <<= 1) {
      unsigned u0 = __shfl_up(s0, o, 64);
      unsigned u1 = __shfl_up(s1, o, 64);
      if (tid >= o) { s0 += u0; s1 += u1; }
    }
    unsigned tot0 = __shfl(s0, 63, 64);
    excl[tid] = s0 - v0;
    excl[tid + 64] = tot0 + s1 - v1;
  }
  __syncthreads();
  if (tid < 128) {
    int node = (b << 7) + tid;
    if (node < N) {
      offs[node] = t0 + excl[tid];
      dinv[node] = 1.0f / fmaxf((float)hist[tid], 1.0f);
    }
  }
  if (b == 0 && tid == 255) offs[N] = (unsigned)E;
  for (unsigned i = tid; i < cnt; i += 256) {
    int nl = (int)ldst[i];
    unsigned slot = excl[nl] + atomicAdd(&cur[nl], 1u);
    csr_src[t0 + slot] = lsrc[i];
  }
}

// ================= gathers =================
// Tail-merged: remainder (<16 edges) handled in ONE predicated 4-deep iteration;
// clamped duplicate loads hit the same in-flight cache line (free).

#define GATHER_BODY(TABLE)                                                       \
  const int node = (blockIdx.x * 256 + threadIdx.x) >> 6;                        \
  if (node >= N) return;                                                         \
  const int lane = threadIdx.x & 63;                                             \
  const int eslot = lane >> 4;                                                   \
  const int col = lane & 15;                                                     \
  const unsigned beg = off[node], end = off[node + 1];                           \
  const ushort* fbase = (TABLE) + col * 8;                                       \
  float acc[8];                                                                  \
  _Pragma("unroll") for (int t = 0; t < 8; ++t) acc[t] = 0.f;                    \
  auto accum = [&](int4 v) {                                                     \
    unsigned w0 = (unsigned)v.x, w1 = (unsigned)v.y;                             \
    unsigned w2 = (unsigned)v.z, w3 = (unsigned)v.w;                             \
    acc[0] += __uint_as_float(w0 << 16);                                         \
    acc[1] += __uint_as_float(w0 & 0xFFFF0000u);                                 \
    acc[2] += __uint_as_float(w1 << 16);                                         \
    acc[3] += __uint_as_float(w1 & 0xFFFF0000u);                                 \
    acc[4] += __uint_as_float(w2 << 16);                                         \
    acc[5] += __uint_as_float(w2 & 0xFFFF0000u);                                 \
    acc[6] += __uint_as_float(w3 << 16);                                         \
    acc[7] += __uint_as_float(w3 & 0xFFFF0000u);                                 \
  };                                                                             \
  unsigned base = beg;                                                           \
  for (; base + 16 <= end; base += 16) {                                         \
    int s0 = csr_src[base + eslot];                                              \
    int s1 = csr_src[base + 4 + eslot];                                          \
    int s2 = csr_src[base + 8 + eslot];                                          \
    int s3 = csr_src[base + 12 + eslot];                                         \
    int4 v0 = *(const int4*)(fbase + (size_t)s0 * DIM);                          \
    int4 v1 = *(const int4*)(fbase + (size_t)s1 * DIM);                          \
    int4 v2 = *(const int4*)(fbase + (size_t)s2 * DIM);                          \
    int4 v3 = *(const int4*)(fbase + (size_t)s3 * DIM);                          \
    accum(v0); accum(v1); accum(v2); accum(v3);                                  \
  }                                                                              \
  if (base < end) {                                                              \
    unsigned e0 = base + eslot, e1 = base + 4 + eslot;                           \
    unsigned e2 = base + 8 + eslot, e3 = base + 12 + eslot;                      \
    int s0 = csr_src[e0 < end ? e0 : end - 1];                                   \
    int s1 = csr_src[e1 < end ? e1 : end - 1];                                   \
    int s2 = csr_src[e2 < end ? e2 : end - 1];                                   \
    int s3 = csr_src[e3 < end ? e3 : end - 1];                                   \
    int4 v0 = *(const int4*)(fbase + (size_t)s0 * DIM);                          \
    int4 v1 = *(const int4*)(fbase + (size_t)s1 * DIM);                          \
    int4 v2 = *(const int4*)(fbase + (size_t)s2 * DIM);                          \
    int4 v3 = *(const int4*)(fbase + (size_t)s3 * DIM);                          \
    if (e0 < end) accum(v0);                                                     \
    if (e1 < end) accum(v1);                                                     \
    if (e2 < end) accum(v2);                                                     \
    if (e3 < end) accum(v3);                                                     \
  }                                                                              \
  _Pragma("unroll") for (int t = 0; t < 8; ++t) {                                \
    acc[t] += __shfl_xor(acc[t], 32, 64);                                        \
    acc[t] += __shfl_xor(acc[t], 16, 64);                                        \
  }

// ---- gather_wave: agg(feat) * dinv -> aggH bf16 (layer 1) ----
__global__ __launch_bounds__(256) void gather_wave_kernel(
    const ushort* __restrict__ featH, const int* __restrict__ csr_src,
    const unsigned* __restrict__ off, const float* __restrict__ dinv,
    ushort* __restrict__ aggH, int N) {
  GATHER_BODY(featH)
  if (eslot == 0) {
    float di = dinv[node];
    unsigned ph[4];
#pragma unroll
    for (int t = 0; t < 4; ++t) {
      ph[t] = (unsigned)f2bf(acc[2 * t] * di) | ((unsigned)f2bf(acc[2 * t + 1] * di) << 16);
    }
    *(int4*)(aggH + (size_t)node * DIM + col * 8) =
        make_int4((int)ph[0], (int)ph[1], (int)ph[2], (int)ph[3]);
  }
}

// ---- gather2: agg(h1l), fused h2=relu(.+h1r) + lin3 dot -> y[N][4] (R2-proven) ----
__global__ __launch_bounds__(256) void gather2_kernel(
    const ushort* __restrict__ h1l, const int* __restrict__ csr_src,
    const unsigned* __restrict__ off, const float* __restrict__ dinv,
    const ushort* __restrict__ h1r, const float* __restrict__ W3l,
    const float* __restrict__ W3r, float* __restrict__ y, int N) {
  GATHER_BODY(h1l)
  if (eslot == 0) {
    float di = dinv[node];
    int4 xv = *(const int4*)(h1r + (size_t)node * DIM + col * 8);
    unsigned w0 = (unsigned)xv.x, w1 = (unsigned)xv.y;
    unsigned w2 = (unsigned)xv.z, w3 = (unsigned)xv.w;
    float h[8];
    h[0] = fmaxf(acc[0] * di + __uint_as_float(w0 << 16), 0.f);
    h[1] = fmaxf(acc[1] * di + __uint_as_float(w0 & 0xFFFF0000u), 0.f);
    h[2] = fmaxf(acc[2] * di + __uint_as_float(w1 << 16), 0.f);
    h[3] = fmaxf(acc[3] * di + __uint_as_float(w1 & 0xFFFF0000u), 0.f);
    h[4] = fmaxf(acc[4] * di + __uint_as_float(w2 << 16), 0.f);
    h[5] = fmaxf(acc[5] * di + __uint_as_float(w2 & 0xFFFF0000u), 0.f);
    h[6] = fmaxf(acc[6] * di + __uint_as_float(w3 << 16), 0.f);
    h[7] = fmaxf(acc[7] * di + __uint_as_float(w3 & 0xFFFF0000u), 0.f);
    const int d0 = col * 8;
    float y0 = 0.f, y1 = 0.f, y2 = 0.f, y3 = 0.f;
#pragma unroll
    for (int t = 0; t < 8; t += 2) {  // W3 rows (d0+t, d0+t+1); 16B-aligned float4
      float4 wl = *(const float4*)(W3l + (size_t)(d0 + t) * 2);
      float4 wr = *(const float4*)(W3r + (size_t)(d0 + t) * 2);
      y0 += h[t] * wl.x + h[t + 1] * wl.z;
      y1 += h[t] * wl.y + h[t + 1] * wl.w;
      y2 += h[t] * wr.x + h[t + 1] * wr.z;
      y3 += h[t] * wr.y + h[t + 1] * wr.w;
    }
#pragma unroll
    for (int o = 1; o < 16; o <<= 1) {  // reduce across lanes 0..15 (all active)
      y0 += __shfl_xor(y0, o, 64);
      y1 += __shfl_xor(y1, o, 64);
      y2 += __shfl_xor(y2, o, 64);
      y3 += __shfl_xor(y3, o, 64);
    }
    if (lane == 0) *(float4*)(y + (size_t)node * 4) = make_float4(y0, y1, y2, y3);
  }
}

// ---- MFMA SAGE layer 1: h1 = relu(agg@W1l + x@W1r + b1), in-place over xh ----
__global__ __launch_bounds__(256) void sage_mfma_kernel(
    const ushort* __restrict__ aggH, const ushort* xH,
    const ushort* __restrict__ WlH, const ushort* __restrict__ WrH,
    const float* __restrict__ bias, ushort* __restrict__ outH, int N) {
  __shared__ ushort As[128 * 64];  // 16 KB
  __shared__ ushort Bs[128 * 64];  // 16 KB

  const int tid = threadIdx.x;
  const int bm = blockIdx.x * 128;
  const int wave = tid >> 6;
  const int lane = tid & 63;
  const int l15 = lane & 15;
  const int quad = lane >> 4;
  const int wm = wave >> 1;
  const int wn = wave & 1;

  f32x4 acc[4][4];
#pragma unroll
  for (int i = 0; i < 4; ++i)
#pragma unroll
    for (int j = 0; j < 4; ++j) acc[i][j] = (f32x4){0.f, 0.f, 0.f, 0.f};

  for (int g = 0; g < 4; ++g) {
    const ushort* Ap = (g < 2) ? aggH : xH;
    const ushort* Wp = (g < 2) ? WlH : WrH;
    const int kt = (g & 1) << 6;
    __syncthreads();
#pragma unroll
    for (int c = 0; c < 4; ++c) {
      int flat = c * 256 + tid;
      int row = flat >> 3;
      int kg = flat & 7;
      int swz = (kg ^ (row & 7)) << 3;
      int grow = bm + row;
      if (grow >= N) grow = N - 1;
      *(int4*)(&As[row * 64 + swz]) = *(const int4*)(Ap + (size_t)grow * DIM + kt + kg * 8);
      *(int4*)(&Bs[row * 64 + swz]) = *(const int4*)(Wp + (size_t)row * DIM + kt + kg * 8);
    }
    __syncthreads();
#pragma unroll
    for (int ks = 0; ks < 2; ++ks) {
      bf16x8 af[4], bfr[4];
      int kg = (ks << 2) + quad;
#pragma unroll
      for (int i = 0; i < 4; ++i) {
        int ar = (wm << 6) + (i << 4) + l15;
        af[i] = *(const bf16x8*)(&As[ar * 64 + ((kg ^ (ar & 7)) << 3)]);
        int br = (wn << 6) + (i << 4) + l15;
        bfr[i] = *(const bf16x8*)(&Bs[br * 64 + ((kg ^ (br & 7)) << 3)]);
      }
#pragma unroll
      for (int i = 0; i < 4; ++i)
#pragma unroll
        for (int j = 0; j < 4; ++j)
          acc[i][j] = __builtin_amdgcn_mfma_f32_16x16x32_bf16(af[i], bfr[j], acc[i][j], 0, 0, 0);
    }
  }

  float bv[4];
#pragma unroll
  for (int j = 0; j < 4; ++j) bv[j] = bias[(wn << 6) + (j << 4) + l15];

  // epilogue: restage relu(acc+b) through LDS -> coalesced int4 writes
  __syncthreads();
#pragma unroll
  for (int i = 0; i < 4; ++i)
#pragma unroll
    for (int j = 0; j < 4; ++j)
#pragma unroll
      for (int r = 0; r < 4; ++r) {
        int row = (wm << 6) + (i << 4) + (quad << 2) + r;
        int colc = (wn << 6) + (j << 4) + l15;
        ((ushort*)As)[((row & 63) << 7) + colc + ((row >> 6) << 13)] =
            f2bf(fmaxf(acc[i][j][r] + bv[j], 0.f));
      }
  __syncthreads();
#pragma unroll
  for (int c = 0; c < 8; ++c) {
    int flat = c * 256 + tid;  // int4 id 0..2047 over 128x128
    int row = flat >> 4;
    int grow = bm + row;
    if (grow < N)
      *(int4*)(outH + (size_t)grow * DIM + (flat & 15) * 8) =
          *(const int4*)((const ushort*)As + flat * 8);
  }
}

// ---- gemm2_dual: h1l = h1@W2l, h1r = h1@W2r + b2 -- h1 read ONCE, LDS-staged writes ----
__global__ __launch_bounds__(256) void gemm2_dual_kernel(
    const ushort* __restrict__ h1, const ushort* __restrict__ tabs2,
    const float* __restrict__ b2, ushort* __restrict__ h1l, ushort* __restrict__ h1r, int N) {
  __shared__ ushort L[3 * 128 * 64];  // 48 KB: As | Bs0 (W2l) | Bs1 (W2r)
  ushort* As = L;
  ushort* Bs0 = L + 8192;
  ushort* Bs1 = L + 16384;
  const int tid = threadIdx.x;
  const int bm = blockIdx.x * 128;
  const int wave = tid >> 6;
  const int lane = tid & 63;
  const int l15 = lane & 15;
  const int quad = lane >> 4;
  const int wm = wave >> 1;
  const int wn = wave & 1;

  f32x4 accl[4][4], accr[4][4];
#pragma unroll
  for (int i = 0; i < 4; ++i)
#pragma unroll
    for (int j = 0; j < 4; ++j) {
      accl[i][j] = (f32x4){0.f, 0.f, 0.f, 0.f};
      accr[i][j] = (f32x4){0.f, 0.f, 0.f, 0.f};
    }

  for (int g = 0; g < 2; ++g) {
    const int kt = g << 6;
    __syncthreads();
#pragma unroll
    for (int c = 0; c < 4; ++c) {
      int flat = c * 256 + tid;
      int row = flat >> 3;
      int kg = flat & 7;
      int swz = (kg ^ (row & 7)) << 3;
      int grow = bm + row;
      if (grow >= N) grow = N - 1;
      *(int4*)(&As[row * 64 + swz]) = *(const int4*)(h1 + (size_t)grow * DIM + kt + kg * 8);
      *(int4*)(&Bs0[row * 64 + swz]) = *(const int4*)(tabs2 + (size_t)row * DIM + kt + kg * 8);
      *(int4*)(&Bs1[row * 64 + swz]) =
          *(const int4*)(tabs2 + 16384 + (size_t)row * DIM + kt + kg * 8);
    }
    __syncthreads();
#pragma unroll
    for (int ks = 0; ks < 2; ++ks) {
      bf16x8 af[4], bl[4], br[4];
      int kg = (ks << 2) + quad;
#pragma unroll
      for (int i = 0; i < 4; ++i) {
        int ar = (wm << 6) + (i << 4) + l15;
        af[i] = *(const bf16x8*)(&As[ar * 64 + ((kg ^ (ar & 7)) << 3)]);
        int nr = (wn << 6) + (i << 4) + l15;
        bl[i] = *(const bf16x8*)(&Bs0[nr * 64 + ((kg ^ (nr & 7)) << 3)]);
        br[i] = *(const bf16x8*)(&Bs1[nr * 64 + ((kg ^ (nr & 7)) << 3)]);
      }
#pragma unroll
      for (int i = 0; i < 4; ++i)
#pragma unroll
        for (int j = 0; j < 4; ++j) {
          accl[i][j] = __builtin_amdgcn_mfma_f32_16x16x32_bf16(af[i], bl[j], accl[i][j], 0, 0, 0);
          accr[i][j] = __builtin_amdgcn_mfma_f32_16x16x32_bf16(af[i], br[j], accr[i][j], 0, 0, 0);
        }
    }
  }

  float bv[4];
#pragma unroll
  for (int j = 0; j < 4; ++j) bv[j] = b2[(wn << 6) + (j << 4) + l15];

  // epilogue: restage each mat through L[0..16383] (32 KB) -> coalesced int4 writes
#pragma unroll
  for (int m = 0; m < 2; ++m) {
    __syncthreads();
#pragma unroll
    for (int i = 0; i < 4; ++i)
#pragma unroll
      for (int j = 0; j < 4; ++j)
#pragma unroll
        for (int r = 0; r < 4; ++r) {
          int row = (wm << 6) + (i << 4) + (quad << 2) + r;
          int colc = (wn << 6) + (j << 4) + l15;
          float v = m ? (accr[i][j][r] + bv[j]) : accl[i][j][r];
          L[row * 128 + colc] = f2bf(v);
        }
    __syncthreads();
    ushort* out = m ? h1r : h1l;
#pragma unroll
    for (int c = 0; c < 8; ++c) {
      int flat = c * 256 + tid;  // int4 id 0..2047
      int row = flat >> 4;
      int grow = bm + row;
      if (grow < N)
        *(int4*)(out + (size_t)grow * DIM + (flat & 15) * 8) = *(const int4*)(&L[flat * 8]);
    }
  }
}

// ---- layer 3: 2-dim CSR gather + bias + relu + log_softmax ----
__global__ __launch_bounds__(256) void final3_kernel(const float* __restrict__ y,
                                                     const int* __restrict__ csr_src,
                                                     const unsigned* __restrict__ off,
                                                     const float* __restrict__ dinv,
                                                     const float* __restrict__ b3,
                                                     float* __restrict__ out, int N) {
  int n = blockIdx.x * 256 + threadIdx.x;
  if (n >= N) return;
  unsigned beg = off[n], end = off[n + 1];
  float s0 = 0.f, s1 = 0.f;
  for (unsigned e = beg; e < end; ++e) {
    int s = csr_src[e];
    float2 v = *reinterpret_cast<const float2*>(&y[(size_t)s * 4]);
    s0 += v.x; s1 += v.y;
  }
  float di = dinv[n];
  float o0 = fmaxf(s0 * di + y[(size_t)n * 4 + 2] + b3[0], 0.f);
  float o1 = fmaxf(s1 * di + y[(size_t)n * 4 + 3] + b3[1], 0.f);
  float m = fmaxf(o0, o1);
  float l = m + logf(expf(o0 - m) + expf(o1 - m));
  out[n * 2 + 0] = o0 - l;
  out[n * 2 + 1] = o1 - l;
}

extern "C" void kernel_launch(void* const* d_in, const int* in_sizes, int n_in,
                              void* d_out, int out_size, void* d_ws, size_t ws_size,
                              hipStream_t stream) {
  const float* x   = (const float*)d_in[0];
  const int*   ei  = (const int*)d_in[1];
  const float* W1l = (const float*)d_in[2];
  const float* W1r = (const float*)d_in[3];
  const float* b1  = (const float*)d_in[4];
  const float* W2l = (const float*)d_in[5];
  const float* W2r = (const float*)d_in[6];
  const float* b2  = (const float*)d_in[7];
  const float* W3l = (const float*)d_in[8];
  const float* W3r = (const float*)d_in[9];
  const float* b3  = (const float*)d_in[10];

  const int N = in_sizes[0] / DIM;  // 100000
  const int E = in_sizes[1] / 2;    // 1600000
  const int* src = ei;
  const int* dst = ei + E;

  const int NBUCK = (N + 127) >> 7;            // 782 buckets (128 nodes each)
  const int NB    = (E + 2047) / 2048;         // 782 count/scatter blocks
  const long total_f = (long)N * DIM;
  const int CB    = (int)((total_f / 4 + 2047) / 2048);  // 1563 cast blocks

  char* ws = (char*)d_ws;
  size_t off_b = 0;
  auto alloc = [&](size_t bytes) {
    void* p = ws + off_b;
    off_b = (off_b + bytes + 255) & ~(size_t)255;
    return p;
  };
  unsigned* counts  = (unsigned*)alloc((size_t)NB * NBUCK * 4);  // 2.45 MB
  unsigned* totals  = (unsigned*)alloc((size_t)(NBUCK + 1) * 4);
  // shared_ region (25.6 MB): pairs (6.4, read last by fine) -> aggH (layer 1,
  // read last by sage_mfma) -> h1l (written by gemm2_dual strictly afterwards).
  void*     shared_ = alloc((size_t)N * DIM * 2);
  unsigned* pairs   = (unsigned*)shared_;
  ushort*   aggH    = (ushort*)shared_;
  ushort*   h1l     = (ushort*)shared_;
  int*      csr_src = (int*)alloc((size_t)E * 4);
  unsigned* offs    = (unsigned*)alloc((size_t)(N + 1) * 4);
  float*    dinv    = (float*)alloc((size_t)N * 4);
  ushort*   xh      = (ushort*)alloc((size_t)N * DIM * 2);
  ushort*   tabs    = (ushort*)alloc((size_t)4 * 16384 * 2);
  float*    y       = (float*)alloc((size_t)N * 4 * 4);
  ushort*   h1r     = (ushort*)alloc((size_t)N * DIM * 2);
  // total ~ 88 MB

  // ---- CSR build (no global atomics, no memset) ----
  count_cast_kernel<<<NB + CB + 256, 256, 0, stream>>>(
      dst, counts, E, NB, NBUCK, x, xh, total_f, W1l, W1r, W2l, W2r, tabs, CB);
  colscan_kernel<<<(NBUCK + 3) / 4, 256, 0, stream>>>(counts, totals, NB, NBUCK);
  totscan_kernel<<<1, 256, 0, stream>>>(totals, NBUCK, E);
  cscatter_kernel<<<NB, 256, 0, stream>>>(src, dst, counts, totals, pairs, E, NBUCK);
  fine_kernel<<<NBUCK, 256, 0, stream>>>(pairs, totals, csr_src, offs, dinv, N, NBUCK, E);

  const ushort* W1lH = tabs;
  const ushort* W1rH = tabs + 16384;
  const ushort* tabs2 = tabs + 32768;  // W2l | W2r
  const int G = (N + 127) / 128;
  const int gather_grid = (N + 3) / 4;  // one wave per node

  // ---- layer 1: h1 = relu(agg@W1l + x@W1r + b1), in-place over xh ----
  gather_wave_kernel<<<gather_grid, 256, 0, stream>>>(xh, csr_src, offs, dinv, aggH, N);
  sage_mfma_kernel<<<G, 256, 0, stream>>>(aggH, xh, W1lH, W1rH, b1, xh, N);
  // ---- layer 2 via linearity: h1l = h1@W2l, h1r = h1@W2r + b2 (h1 read once) ----
  gemm2_dual_kernel<<<G, 256, 0, stream>>>(xh, tabs2, b2, h1l, h1r, N);
  // ---- layer 2 epilogue + lin3: h2 = relu(mean_agg(h1l) + h1r); y = h2@[W3l|W3r] ----
  gather2_kernel<<<gather_grid, 256, 0, stream>>>(h1l, csr_src, offs, dinv, h1r, W3l, W3r, y, N);
  // ---- layer 3 ----
  final3_kernel<<<(N + 255) / 256, 256, 0, stream>>>(y, csr_src, offs, dinv, b3, (float*)d_out, N);
}